// Round 5
// baseline (431.504 us; speedup 1.0000x reference)
//
#include <hip/hip_runtime.h>
#include <hip/hip_bf16.h>

typedef __attribute__((ext_vector_type(8)))  short short8;
typedef __attribute__((ext_vector_type(16))) float f32x16;

#define DIM   64
#define K_CL  512
#define N_PTS 524288
#define OUTSZ (K_CL * DIM + K_CL)   // 33280

// ---------------------------------------------------------------------------
// prep: hc2[k] = 0.5*||c_k||^2 ; chi/clo = bf16 hi/lo split of NEGATED centers
// ---------------------------------------------------------------------------
__global__ void prep_kernel(const float* __restrict__ c,
                            unsigned short* __restrict__ chi,
                            unsigned short* __restrict__ clo,
                            float* __restrict__ hc2) {
    int k = blockIdx.x * blockDim.x + threadIdx.x;
    if (k >= K_CL) return;
    float s = 0.f;
    for (int d = 0; d < DIM; ++d) {
        float v = c[k * DIM + d];
        s += v * v;
        float nv = -v;
        unsigned int u  = __builtin_bit_cast(unsigned int, nv);
        unsigned int hr = (u + 0x7FFFu + ((u >> 16) & 1u)) & 0xFFFF0000u;
        chi[k * DIM + d] = (unsigned short)(hr >> 16);
        float lo = nv - __builtin_bit_cast(float, hr);
        unsigned int ul = __builtin_bit_cast(unsigned int, lo);
        unsigned int lr = ul + 0x7FFFu + ((ul >> 16) & 1u);
        clo[k * DIM + d] = (unsigned short)(lr >> 16);
    }
    hc2[k] = 0.5f * s;
}

// pack two fp32 -> one u32 of 2x bf16 (RNE) via compiler cvt_pk path
__device__ inline unsigned int pk_bf16(float a, float b) {
    float2 t; t.x = a; t.y = b;
    __hip_bfloat162 h2 = __float22bfloat162_rn(t);
    unsigned int u;
    __builtin_memcpy(&u, &h2, 4);
    return u;
}

// split 8 fp32 (two float4) into bf16 hi + lo fragments
__device__ inline void split8(const float4& a, const float4& b,
                              short8& hi, short8& lo) {
    float f[8] = {a.x, a.y, a.z, a.w, b.x, b.y, b.z, b.w};
    unsigned int hw[4], lw[4];
    float hf[8];
#pragma unroll
    for (int p = 0; p < 4; ++p) {
        unsigned int u = pk_bf16(f[2*p], f[2*p+1]);
        hw[p] = u;
        hf[2*p]   = __builtin_bit_cast(float, u << 16);
        hf[2*p+1] = __builtin_bit_cast(float, u & 0xFFFF0000u);
    }
#pragma unroll
    for (int p = 0; p < 4; ++p)
        lw[p] = pk_bf16(f[2*p] - hf[2*p], f[2*p+1] - hf[2*p+1]);
    uint4 hu; hu.x = hw[0]; hu.y = hw[1]; hu.z = hw[2]; hu.w = hw[3];
    uint4 lu; lu.x = lw[0]; lu.y = lw[1]; lu.z = lw[2]; lu.w = lw[3];
    hi = __builtin_bit_cast(short8, hu);
    lo = __builtin_bit_cast(short8, lu);
}

// ---------------------------------------------------------------------------
// assign: 2048 blocks x 512 thr (8 waves). Wave owns 64 centers resident in
// VGPRs; 8 tiles of 32 points. Per-point winner via packed u64 atomicMin in
// LDS (no per-tile barriers). Bias (0.5*||c||^2) resident in VGPRs.
// ---------------------------------------------------------------------------
__global__ __launch_bounds__(512)
void assign_kernel(const float* __restrict__ x,
                   const unsigned short* __restrict__ chi_g,
                   const unsigned short* __restrict__ clo_g,
                   const float* __restrict__ hc2g,
                   unsigned int* __restrict__ assign) {
    __shared__ float lds_hc2[K_CL];
    __shared__ unsigned long long lds_best[256];

    const int tid  = threadIdx.x;
    const int wave = tid >> 6;
    const int lane = tid & 63;
    const int l31  = lane & 31;
    const int h    = lane >> 5;

    lds_hc2[tid] = hc2g[tid];                 // blockDim == K_CL
    if (tid < 256) lds_best[tid] = ~0ull;

    // resident center fragments
    short8 cH[2][4], cL[2][4];
#pragma unroll
    for (int ct = 0; ct < 2; ++ct) {
        int row = wave * 64 + ct * 32 + l31;
#pragma unroll
        for (int ks = 0; ks < 4; ++ks) {
            size_t off = (size_t)row * DIM + ks * 16 + h * 8;
            cH[ct][ks] = *(const short8*)(chi_g + off);
            cL[ct][ks] = *(const short8*)(clo_g + off);
        }
    }
    __syncthreads();

    // resident bias: acc reg r -> center row (r&3)+8*(r>>2)+4h (+32 for acc1)
    f32x16 bias0, bias1;
#pragma unroll
    for (int r = 0; r < 16; ++r) {
        int ro = (r & 3) + 8 * (r >> 2) + 4 * h;
        bias0[r] = lds_hc2[wave * 64 + ro];
        bias1[r] = lds_hc2[wave * 64 + 32 + ro];
    }

    const unsigned int base_id = wave * 64 + 4 * h;

    for (int t = 0; t < 8; ++t) {
        const int tb = (blockIdx.x * 8 + t) * 32;
        const float* px = x + (size_t)(tb + l31) * DIM + h * 8;

        float4 xf[4][2];
#pragma unroll
        for (int ks = 0; ks < 4; ++ks) {
            xf[ks][0] = *(const float4*)(px + ks * 16);
            xf[ks][1] = *(const float4*)(px + ks * 16 + 4);
        }

        f32x16 acc0 = bias0, acc1 = bias1;
#pragma unroll
        for (int ks = 0; ks < 4; ++ks) {
            short8 xh, xl;
            split8(xf[ks][0], xf[ks][1], xh, xl);
            acc0 = __builtin_amdgcn_mfma_f32_32x32x16_bf16(cH[0][ks], xh, acc0, 0, 0, 0);
            acc1 = __builtin_amdgcn_mfma_f32_32x32x16_bf16(cH[1][ks], xh, acc1, 0, 0, 0);
            acc0 = __builtin_amdgcn_mfma_f32_32x32x16_bf16(cH[0][ks], xl, acc0, 0, 0, 0);
            acc1 = __builtin_amdgcn_mfma_f32_32x32x16_bf16(cH[1][ks], xl, acc1, 0, 0, 0);
            acc0 = __builtin_amdgcn_mfma_f32_32x32x16_bf16(cL[0][ks], xh, acc0, 0, 0, 0);
            acc1 = __builtin_amdgcn_mfma_f32_32x32x16_bf16(cL[1][ks], xh, acc1, 0, 0, 0);
        }

        // in-lane argmin, ids ascending -> strict < = first occurrence
        float bv = acc0[0];
        unsigned int boff = 0;
#pragma unroll
        for (int r = 1; r < 16; ++r) {
            unsigned int off = (r & 3) + 8 * (r >> 2);
            float v = acc0[r];
            if (v < bv) { bv = v; boff = off; }
        }
#pragma unroll
        for (int r = 0; r < 16; ++r) {
            unsigned int off = 32 + (r & 3) + 8 * (r >> 2);
            float v = acc1[r];
            if (v < bv) { bv = v; boff = off; }
        }

        unsigned int ub = __builtin_bit_cast(unsigned int, bv);
        ub ^= (unsigned int)(((int)ub) >> 31) | 0x80000000u;   // orderable
        unsigned long long pk =
            ((unsigned long long)ub << 32) | (unsigned long long)(base_id + boff);
        atomicMin(&lds_best[t * 32 + l31], pk);   // both halves: same point slot
    }
    __syncthreads();

    if (tid < 256)
        assign[blockIdx.x * 256 + tid] = (unsigned int)(lds_best[tid] & 0xFFFFFFFFu);
}

// ---------------------------------------------------------------------------
// reduce: P blocks, each owns a contiguous point range; LDS padded partial
// sums (atomic, stride 65); flush = private slab write (NO global atomics).
// ---------------------------------------------------------------------------
__global__ __launch_bounds__(1024)
void reduce_kernel(const float* __restrict__ x,
                   const unsigned int* __restrict__ assign,
                   float* __restrict__ partials, int iters) {
    __shared__ float lds[K_CL * 65 + K_CL];
    for (int i = threadIdx.x; i < K_CL * 65 + K_CL; i += 1024) lds[i] = 0.f;
    __syncthreads();

    const size_t base = (size_t)blockIdx.x * iters * 1024 + threadIdx.x;
    for (int it = 0; it < iters; ++it) {
        size_t p = base + (size_t)it * 1024;
        const float4* xp = (const float4*)(x + p * DIM);
        int a = assign[p];
        float* dst = lds + a * 65;
#pragma unroll
        for (int i = 0; i < 16; ++i) {
            float4 v = xp[i];
            atomicAdd(&dst[4 * i + 0], v.x);
            atomicAdd(&dst[4 * i + 1], v.y);
            atomicAdd(&dst[4 * i + 2], v.z);
            atomicAdd(&dst[4 * i + 3], v.w);
        }
        atomicAdd(&lds[K_CL * 65 + a], 1.f);
    }
    __syncthreads();

    float* dst = partials + (size_t)blockIdx.x * OUTSZ;
    for (int i = threadIdx.x; i < K_CL * DIM; i += 1024) {
        int k = i >> 6, d = i & 63;
        dst[i] = lds[k * 65 + d];
    }
    if (threadIdx.x < K_CL)
        dst[K_CL * DIM + threadIdx.x] = lds[K_CL * 65 + threadIdx.x];
}

// ---------------------------------------------------------------------------
// final: sum P slabs + divide + empty-cluster fallback + counts
// ---------------------------------------------------------------------------
__global__ void final_kernel(const float* __restrict__ partials,
                             const float* __restrict__ centers,
                             float* __restrict__ out, int P) {
    int i = blockIdx.x * 256 + threadIdx.x;
    if (i >= OUTSZ) return;
    if (i < K_CL * DIM) {
        int k = i >> 6;
        float s = 0.f, c = 0.f;
        for (int b = 0; b < P; ++b) {
            s += partials[(size_t)b * OUTSZ + i];
            c += partials[(size_t)b * OUTSZ + K_CL * DIM + k];
        }
        out[i] = (c > 0.f) ? (s / c) : centers[i];
    } else {
        int k = i - K_CL * DIM;
        float c = 0.f;
        for (int b = 0; b < P; ++b)
            c += partials[(size_t)b * OUTSZ + K_CL * DIM + k];
        out[i] = c;
    }
}

extern "C" void kernel_launch(void* const* d_in, const int* in_sizes, int n_in,
                              void* d_out, int out_size, void* d_ws, size_t ws_size,
                              hipStream_t stream) {
    const float* x       = (const float*)d_in[0];
    const float* centers = (const float*)d_in[1];

    char* ws = (char*)d_ws;
    unsigned short* chi    = (unsigned short*)(ws);             // 64 KiB
    unsigned short* clo    = (unsigned short*)(ws + 65536);     // 64 KiB
    float*          hc2    = (float*)(ws + 131072);             // 2 KiB
    unsigned int*   assign = (unsigned int*)(ws + 133120);      // 2 MiB
    const size_t    fixed  = 133120 + (size_t)N_PTS * 4;        // 2230272
    float*          partials = (float*)(ws + fixed);

    // P = pow2 number of reduce blocks that fits in ws
    size_t avail = (ws_size > fixed) ? (ws_size - fixed) : 0;
    int P = (int)(avail / (OUTSZ * 4));
    if (P > 256) P = 256;
    if (P < 1)  P = 1;
    while (P & (P - 1)) P &= P - 1;   // round down to power of 2
    int iters = N_PTS / (P * 1024);

    prep_kernel<<<8, 64, 0, stream>>>(centers, chi, clo, hc2);
    assign_kernel<<<2048, 512, 0, stream>>>(x, chi, clo, hc2, assign);
    reduce_kernel<<<P, 1024, 0, stream>>>(x, assign, partials, iters);
    final_kernel<<<(OUTSZ + 255) / 256, 256, 0, stream>>>(
        partials, centers, (float*)d_out, P);
}

// Round 6
// 302.841 us; speedup vs baseline: 1.4249x; 1.4249x over previous
//
#include <hip/hip_runtime.h>
#include <hip/hip_bf16.h>

typedef __attribute__((ext_vector_type(8)))  short short8;
typedef __attribute__((ext_vector_type(16))) float f32x16;

#define DIM   64
#define K_CL  512
#define N_PTS 524288
#define OUTSZ (K_CL * DIM + K_CL)   // 33280

// pack two fp32 -> one u32 of 2x bf16 (RNE) via compiler cvt_pk path
__device__ inline unsigned int pk_bf16(float a, float b) {
    float2 t; t.x = a; t.y = b;
    __hip_bfloat162 h2 = __float22bfloat162_rn(t);
    unsigned int u;
    __builtin_memcpy(&u, &h2, 4);
    return u;
}

// split float4 -> 2 u32 of bf16-hi, 2 u32 of bf16-lo
__device__ inline void split4(const float4& v, unsigned int hw[2], unsigned int lw[2]) {
    hw[0] = pk_bf16(v.x, v.y);
    hw[1] = pk_bf16(v.z, v.w);
    float hx = __builtin_bit_cast(float, hw[0] << 16);
    float hy = __builtin_bit_cast(float, hw[0] & 0xFFFF0000u);
    float hz = __builtin_bit_cast(float, hw[1] << 16);
    float hv = __builtin_bit_cast(float, hw[1] & 0xFFFF0000u);
    lw[0] = pk_bf16(v.x - hx, v.y - hy);
    lw[1] = pk_bf16(v.z - hz, v.w - hv);
}

// ---------------------------------------------------------------------------
// prep: one 64-lane block per center. hc2 = 0.5*||c||^2 (shuffle reduce);
// chi/clo = bf16 hi/lo of NEGATED center.
// ---------------------------------------------------------------------------
__global__ __launch_bounds__(64)
void prep_kernel(const float* __restrict__ c,
                 unsigned short* __restrict__ chi,
                 unsigned short* __restrict__ clo,
                 float* __restrict__ hc2) {
    const int k = blockIdx.x, d = threadIdx.x;
    float v = c[k * DIM + d];
    float s = v * v;
#pragma unroll
    for (int off = 1; off < 64; off <<= 1) s += __shfl_xor(s, off, 64);

    float nv = -v;
    unsigned int u  = __builtin_bit_cast(unsigned int, nv);
    unsigned int hr = (u + 0x7FFFu + ((u >> 16) & 1u)) & 0xFFFF0000u;
    chi[k * DIM + d] = (unsigned short)(hr >> 16);
    float lo = nv - __builtin_bit_cast(float, hr);
    unsigned int ul = __builtin_bit_cast(unsigned int, lo);
    unsigned int lr = ul + 0x7FFFu + ((ul >> 16) & 1u);
    clo[k * DIM + d] = (unsigned short)(lr >> 16);
    if (d == 0) hc2[k] = 0.5f * s;
}

// ---------------------------------------------------------------------------
// assign: 2048 blocks x 512 thr (8 waves), 8 tiles of 32 points per block.
// Wave owns 64 centers resident in VGPRs. x-tile staged cooperatively to LDS
// as bf16 hi/lo fragments (split done ONCE per block, not per wave), with
// XOR swizzle (p^(f&7)) to break write bank conflicts. Bias (0.5*||c||^2)
// in an LDS table laid out in acc-register order -> broadcast ds_read init.
// Per-point winner via packed u64 atomicMin. Target <=128 regs, 2 blocks/CU.
// ---------------------------------------------------------------------------
__global__ __launch_bounds__(512, 4)
void assign_kernel(const float* __restrict__ x,
                   const unsigned short* __restrict__ chi_g,
                   const unsigned short* __restrict__ clo_g,
                   const float* __restrict__ hc2g,
                   unsigned int* __restrict__ assign) {
    __shared__ unsigned int lds_xh[1024];        // 8 frags * 32 pts * 16B
    __shared__ unsigned int lds_xl[1024];
    __shared__ float lds_bias[512];              // [w][ct][h][r] acc order
    __shared__ unsigned long long lds_best[256];

    const int tid  = threadIdx.x;
    const int wave = tid >> 6;
    const int lane = tid & 63;
    const int l31  = lane & 31;
    const int h    = lane >> 5;

    if (tid < 256) lds_best[tid] = ~0ull;
    {   // bias table: flat idx = w*64 + ct*32 + h*16 + r
        int w = tid >> 6, ct = (tid >> 5) & 1, hh = (tid >> 4) & 1, r = tid & 15;
        lds_bias[tid] = hc2g[w * 64 + ct * 32 + (r & 3) + 8 * (r >> 2) + 4 * hh];
    }

    // resident center fragments (64 VGPRs)
    short8 cH[2][4], cL[2][4];
#pragma unroll
    for (int ct = 0; ct < 2; ++ct) {
        int row = wave * 64 + ct * 32 + l31;
#pragma unroll
        for (int ks = 0; ks < 4; ++ks) {
            size_t off = (size_t)row * DIM + ks * 16 + h * 8;
            cH[ct][ks] = *(const short8*)(chi_g + off);
            cL[ct][ks] = *(const short8*)(clo_g + off);
        }
    }

    // staging constants: thread t stages point p, dims 4*dgrp..+3
    const int p_st  = tid >> 4;
    const int dgrp  = tid & 15;
    const int f_st  = dgrp >> 1;
    const int half  = dgrp & 1;
    const int widx  = f_st * 128 + ((p_st ^ (f_st & 7)) << 2) + half * 2;

    const size_t xbase = (size_t)blockIdx.x * 16384 + tid * 4;
    float4 pf = *(const float4*)(x + xbase);     // prefetch tile 0

    __syncthreads();                             // bias + best-init visible

    const unsigned int base_id = wave * 64 + 4 * h;

    for (int t = 0; t < 8; ++t) {
        // stage current tile (split + swizzled LDS write)
        unsigned int hw2[2], lw2[2];
        split4(pf, hw2, lw2);
        { uint2 w2; w2.x = hw2[0]; w2.y = hw2[1]; *(uint2*)&lds_xh[widx] = w2; }
        { uint2 w2; w2.x = lw2[0]; w2.y = lw2[1]; *(uint2*)&lds_xl[widx] = w2; }
        __syncthreads();

        // issue prefetch for next tile (consumed after compute -> latency hidden)
        if (t < 7) pf = *(const float4*)(x + xbase + (size_t)(t + 1) * 2048);

        // acc init from LDS bias table (broadcast b128 reads)
        f32x16 acc0, acc1;
        {
            const float4* b0 = (const float4*)&lds_bias[wave * 64 + h * 16];
            const float4* b1 = (const float4*)&lds_bias[wave * 64 + 32 + h * 16];
#pragma unroll
            for (int g = 0; g < 4; ++g) {
                float4 a = b0[g], b = b1[g];
                acc0[4*g+0] = a.x; acc0[4*g+1] = a.y; acc0[4*g+2] = a.z; acc0[4*g+3] = a.w;
                acc1[4*g+0] = b.x; acc1[4*g+1] = b.y; acc1[4*g+2] = b.z; acc1[4*g+3] = b.w;
            }
        }

        // per-ks: read frag from LDS, 6 MFMAs (streams regs, small live range)
#pragma unroll
        for (int ks = 0; ks < 4; ++ks) {
            const int f = ks * 2 + h;
            const int ridx = f * 128 + ((l31 ^ (f & 7)) << 2);
            short8 xh = *(const short8*)&lds_xh[ridx];
            short8 xl = *(const short8*)&lds_xl[ridx];
            acc0 = __builtin_amdgcn_mfma_f32_32x32x16_bf16(cH[0][ks], xh, acc0, 0, 0, 0);
            acc1 = __builtin_amdgcn_mfma_f32_32x32x16_bf16(cH[1][ks], xh, acc1, 0, 0, 0);
            acc0 = __builtin_amdgcn_mfma_f32_32x32x16_bf16(cH[0][ks], xl, acc0, 0, 0, 0);
            acc1 = __builtin_amdgcn_mfma_f32_32x32x16_bf16(cH[1][ks], xl, acc1, 0, 0, 0);
            acc0 = __builtin_amdgcn_mfma_f32_32x32x16_bf16(cL[0][ks], xh, acc0, 0, 0, 0);
            acc1 = __builtin_amdgcn_mfma_f32_32x32x16_bf16(cL[1][ks], xh, acc1, 0, 0, 0);
        }

        // in-lane argmin, ids ascending -> strict < = first occurrence
        float bv = acc0[0];
        unsigned int boff = 0;
#pragma unroll
        for (int r = 1; r < 16; ++r) {
            unsigned int off = (r & 3) + 8 * (r >> 2);
            if (acc0[r] < bv) { bv = acc0[r]; boff = off; }
        }
#pragma unroll
        for (int r = 0; r < 16; ++r) {
            unsigned int off = 32 + (r & 3) + 8 * (r >> 2);
            if (acc1[r] < bv) { bv = acc1[r]; boff = off; }
        }

        unsigned int ub = __builtin_bit_cast(unsigned int, bv);
        ub ^= (unsigned int)(((int)ub) >> 31) | 0x80000000u;   // orderable
        unsigned long long pk =
            ((unsigned long long)ub << 32) | (unsigned long long)(base_id + boff);
        atomicMin(&lds_best[t * 32 + l31], pk);
        __syncthreads();                          // protect next tile's stage
    }

    if (tid < 256)
        assign[blockIdx.x * 256 + tid] = (unsigned int)(lds_best[tid] & 0xFFFFFFFFu);
}

// ---------------------------------------------------------------------------
// reduce: 256 blocks x 1024 thr, 2048 pts each; LDS padded partial sums
// (stride 65) + rotated global-atomic flush (stagger line contention).
// ---------------------------------------------------------------------------
__global__ __launch_bounds__(1024)
void reduce_kernel(const float* __restrict__ x,
                   const unsigned int* __restrict__ assign,
                   float* __restrict__ gsums, float* __restrict__ gcnt) {
    __shared__ float lds[K_CL * 65 + K_CL];
    for (int i = threadIdx.x; i < K_CL * 65 + K_CL; i += 1024) lds[i] = 0.f;
    __syncthreads();

    const int pt_base = blockIdx.x * 2048 + threadIdx.x;
#pragma unroll
    for (int it = 0; it < 2; ++it) {
        int p = pt_base + it * 1024;
        const float4* xp = (const float4*)(x + (size_t)p * DIM);
        int a = assign[p];
        float* dst = lds + a * 65;
#pragma unroll
        for (int i = 0; i < 16; ++i) {
            float4 v = xp[i];
            atomicAdd(&dst[4 * i + 0], v.x);
            atomicAdd(&dst[4 * i + 1], v.y);
            atomicAdd(&dst[4 * i + 2], v.z);
            atomicAdd(&dst[4 * i + 3], v.w);
        }
        atomicAdd(&lds[K_CL * 65 + a], 1.f);
    }
    __syncthreads();

    const int rot = (blockIdx.x & 255) << 7;   // rotate flush order per block
    for (int i = threadIdx.x; i < K_CL * DIM; i += 1024) {
        int j = (i + rot) & (K_CL * DIM - 1);
        atomicAdd(&gsums[j], lds[(j >> 6) * 65 + (j & 63)]);
    }
    if (threadIdx.x < K_CL) {
        int j = (threadIdx.x + (blockIdx.x << 1)) & (K_CL - 1);
        atomicAdd(&gcnt[j], lds[K_CL * 65 + j]);
    }
}

// ---------------------------------------------------------------------------
// final: means + empty-cluster fallback + counts -> d_out
// ---------------------------------------------------------------------------
__global__ void final_kernel(const float* __restrict__ gsums,
                             const float* __restrict__ gcnt,
                             const float* __restrict__ centers,
                             float* __restrict__ out) {
    int i = blockIdx.x * 256 + threadIdx.x;
    if (i < K_CL * DIM) {
        int k = i >> 6;
        float c = gcnt[k];
        out[i] = (c > 0.f) ? (gsums[i] / c) : centers[i];
    } else if (i < OUTSZ) {
        out[i] = gcnt[i - K_CL * DIM];
    }
}

extern "C" void kernel_launch(void* const* d_in, const int* in_sizes, int n_in,
                              void* d_out, int out_size, void* d_ws, size_t ws_size,
                              hipStream_t stream) {
    const float* x       = (const float*)d_in[0];
    const float* centers = (const float*)d_in[1];

    char* ws = (char*)d_ws;
    unsigned short* chi    = (unsigned short*)(ws);             // 64 KiB
    unsigned short* clo    = (unsigned short*)(ws + 65536);     // 64 KiB
    float*          hc2    = (float*)(ws + 131072);             // 2 KiB
    unsigned int*   assign = (unsigned int*)(ws + 133120);      // 2 MiB
    float*          gsums  = (float*)(ws + 2230272);            // 128 KiB
    float*          gcnt   = (float*)(ws + 2361344);            // 2 KiB
    // total 2363392 B -- proven available in rounds 1-3

    hipMemsetAsync(gsums, 0, (K_CL * DIM + K_CL) * sizeof(float), stream);
    prep_kernel<<<K_CL, 64, 0, stream>>>(centers, chi, clo, hc2);
    assign_kernel<<<2048, 512, 0, stream>>>(x, chi, clo, hc2, assign);
    reduce_kernel<<<256, 1024, 0, stream>>>(x, assign, gsums, gcnt);
    final_kernel<<<(OUTSZ + 255) / 256, 256, 0, stream>>>(
        gsums, gcnt, centers, (float*)d_out);
}

// Round 7
// 225.459 us; speedup vs baseline: 1.9139x; 1.3432x over previous
//
#include <hip/hip_runtime.h>
#include <hip/hip_bf16.h>

typedef __attribute__((ext_vector_type(8)))  short short8;
typedef __attribute__((ext_vector_type(16))) float f32x16;

#define DIM   64
#define K_CL  512
#define N_PTS 524288
#define OUTSZ (K_CL * DIM + K_CL)   // 33280

// pack two fp32 -> one u32 of 2x bf16 (RNE) via compiler cvt_pk path
__device__ inline unsigned int pk_bf16(float a, float b) {
    float2 t; t.x = a; t.y = b;
    __hip_bfloat162 h2 = __float22bfloat162_rn(t);
    unsigned int u;
    __builtin_memcpy(&u, &h2, 4);
    return u;
}

// split float4 -> 2 u32 of bf16-hi, 2 u32 of bf16-lo
__device__ inline void split4(const float4& v, unsigned int hw[2], unsigned int lw[2]) {
    hw[0] = pk_bf16(v.x, v.y);
    hw[1] = pk_bf16(v.z, v.w);
    float hx = __builtin_bit_cast(float, hw[0] << 16);
    float hy = __builtin_bit_cast(float, hw[0] & 0xFFFF0000u);
    float hz = __builtin_bit_cast(float, hw[1] << 16);
    float hv = __builtin_bit_cast(float, hw[1] & 0xFFFF0000u);
    lw[0] = pk_bf16(v.x - hx, v.y - hy);
    lw[1] = pk_bf16(v.z - hz, v.w - hv);
}

// split 8 fp32 -> hi/lo short8 fragments (slot j = k-slot 8h+j)
__device__ inline void cvt8(const float v[8], short8& hi, short8& lo) {
    unsigned int hw[4], lw[4];
#pragma unroll
    for (int p = 0; p < 4; ++p) {
        hw[p] = pk_bf16(v[2*p], v[2*p+1]);
        float ha = __builtin_bit_cast(float, hw[p] << 16);
        float hb = __builtin_bit_cast(float, hw[p] & 0xFFFF0000u);
        lw[p] = pk_bf16(v[2*p] - ha, v[2*p+1] - hb);
    }
    uint4 hu; hu.x = hw[0]; hu.y = hw[1]; hu.z = hw[2]; hu.w = hw[3];
    uint4 lu; lu.x = lw[0]; lu.y = lw[1]; lu.z = lw[2]; lu.w = lw[3];
    hi = __builtin_bit_cast(short8, hu);
    lo = __builtin_bit_cast(short8, lu);
}

// ---------------------------------------------------------------------------
// prep: one 64-lane block per center. hc2 = 0.5*||c||^2 (shuffle reduce);
// chi/clo = bf16 hi/lo of NEGATED center.
// ---------------------------------------------------------------------------
__global__ __launch_bounds__(64)
void prep_kernel(const float* __restrict__ c,
                 unsigned short* __restrict__ chi,
                 unsigned short* __restrict__ clo,
                 float* __restrict__ hc2) {
    const int k = blockIdx.x, d = threadIdx.x;
    float v = c[k * DIM + d];
    float s = v * v;
#pragma unroll
    for (int off = 1; off < 64; off <<= 1) s += __shfl_xor(s, off, 64);

    float nv = -v;
    unsigned int u  = __builtin_bit_cast(unsigned int, nv);
    unsigned int hr = (u + 0x7FFFu + ((u >> 16) & 1u)) & 0xFFFF0000u;
    chi[k * DIM + d] = (unsigned short)(hr >> 16);
    float lo = nv - __builtin_bit_cast(float, hr);
    unsigned int ul = __builtin_bit_cast(unsigned int, lo);
    unsigned int lr = ul + 0x7FFFu + ((ul >> 16) & 1u);
    clo[k * DIM + d] = (unsigned short)(lr >> 16);
    if (d == 0) hc2[k] = 0.5f * s;
}

// ---------------------------------------------------------------------------
// assign (unchanged from round 6): 2048 blocks x 512 thr, cooperative x
// staging, centers resident in VGPRs, u64 atomicMin winner.
// ---------------------------------------------------------------------------
__global__ __launch_bounds__(512, 4)
void assign_kernel(const float* __restrict__ x,
                   const unsigned short* __restrict__ chi_g,
                   const unsigned short* __restrict__ clo_g,
                   const float* __restrict__ hc2g,
                   unsigned int* __restrict__ assign) {
    __shared__ unsigned int lds_xh[1024];
    __shared__ unsigned int lds_xl[1024];
    __shared__ float lds_bias[512];
    __shared__ unsigned long long lds_best[256];

    const int tid  = threadIdx.x;
    const int wave = tid >> 6;
    const int lane = tid & 63;
    const int l31  = lane & 31;
    const int h    = lane >> 5;

    if (tid < 256) lds_best[tid] = ~0ull;
    {
        int w = tid >> 6, ct = (tid >> 5) & 1, hh = (tid >> 4) & 1, r = tid & 15;
        lds_bias[tid] = hc2g[w * 64 + ct * 32 + (r & 3) + 8 * (r >> 2) + 4 * hh];
    }

    short8 cH[2][4], cL[2][4];
#pragma unroll
    for (int ct = 0; ct < 2; ++ct) {
        int row = wave * 64 + ct * 32 + l31;
#pragma unroll
        for (int ks = 0; ks < 4; ++ks) {
            size_t off = (size_t)row * DIM + ks * 16 + h * 8;
            cH[ct][ks] = *(const short8*)(chi_g + off);
            cL[ct][ks] = *(const short8*)(clo_g + off);
        }
    }

    const int p_st  = tid >> 4;
    const int dgrp  = tid & 15;
    const int f_st  = dgrp >> 1;
    const int half  = dgrp & 1;
    const int widx  = f_st * 128 + ((p_st ^ (f_st & 7)) << 2) + half * 2;

    const size_t xbase = (size_t)blockIdx.x * 16384 + tid * 4;
    float4 pf = *(const float4*)(x + xbase);

    __syncthreads();

    const unsigned int base_id = wave * 64 + 4 * h;

    for (int t = 0; t < 8; ++t) {
        unsigned int hw2[2], lw2[2];
        split4(pf, hw2, lw2);
        { uint2 w2; w2.x = hw2[0]; w2.y = hw2[1]; *(uint2*)&lds_xh[widx] = w2; }
        { uint2 w2; w2.x = lw2[0]; w2.y = lw2[1]; *(uint2*)&lds_xl[widx] = w2; }
        __syncthreads();

        if (t < 7) pf = *(const float4*)(x + xbase + (size_t)(t + 1) * 2048);

        f32x16 acc0, acc1;
        {
            const float4* b0 = (const float4*)&lds_bias[wave * 64 + h * 16];
            const float4* b1 = (const float4*)&lds_bias[wave * 64 + 32 + h * 16];
#pragma unroll
            for (int g = 0; g < 4; ++g) {
                float4 a = b0[g], b = b1[g];
                acc0[4*g+0] = a.x; acc0[4*g+1] = a.y; acc0[4*g+2] = a.z; acc0[4*g+3] = a.w;
                acc1[4*g+0] = b.x; acc1[4*g+1] = b.y; acc1[4*g+2] = b.z; acc1[4*g+3] = b.w;
            }
        }

#pragma unroll
        for (int ks = 0; ks < 4; ++ks) {
            const int f = ks * 2 + h;
            const int ridx = f * 128 + ((l31 ^ (f & 7)) << 2);
            short8 xh = *(const short8*)&lds_xh[ridx];
            short8 xl = *(const short8*)&lds_xl[ridx];
            acc0 = __builtin_amdgcn_mfma_f32_32x32x16_bf16(cH[0][ks], xh, acc0, 0, 0, 0);
            acc1 = __builtin_amdgcn_mfma_f32_32x32x16_bf16(cH[1][ks], xh, acc1, 0, 0, 0);
            acc0 = __builtin_amdgcn_mfma_f32_32x32x16_bf16(cH[0][ks], xl, acc0, 0, 0, 0);
            acc1 = __builtin_amdgcn_mfma_f32_32x32x16_bf16(cH[1][ks], xl, acc1, 0, 0, 0);
            acc0 = __builtin_amdgcn_mfma_f32_32x32x16_bf16(cL[0][ks], xh, acc0, 0, 0, 0);
            acc1 = __builtin_amdgcn_mfma_f32_32x32x16_bf16(cL[1][ks], xh, acc1, 0, 0, 0);
        }

        float bv = acc0[0];
        unsigned int boff = 0;
#pragma unroll
        for (int r = 1; r < 16; ++r) {
            unsigned int off = (r & 3) + 8 * (r >> 2);
            if (acc0[r] < bv) { bv = acc0[r]; boff = off; }
        }
#pragma unroll
        for (int r = 0; r < 16; ++r) {
            unsigned int off = 32 + (r & 3) + 8 * (r >> 2);
            if (acc1[r] < bv) { bv = acc1[r]; boff = off; }
        }

        unsigned int ub = __builtin_bit_cast(unsigned int, bv);
        ub ^= (unsigned int)(((int)ub) >> 31) | 0x80000000u;
        unsigned long long pk =
            ((unsigned long long)ub << 32) | (unsigned long long)(base_id + boff);
        atomicMin(&lds_best[t * 32 + l31], pk);
        __syncthreads();
    }

    if (tid < 256)
        assign[blockIdx.x * 256 + tid] = (unsigned int)(lds_best[tid] & 0xFFFFFFFFu);
}

// ---------------------------------------------------------------------------
// reduce v2: segment-sum as one-hot MFMA. 256 blocks x 512 thr (8 waves).
// Wave owns 64 centers (2 row-tiles); all waves sweep the block's 2048
// points in 16-pt chunks. A = one-hot(assign) built in-register; B = x read
// straight from global in fragment order (half-wave 128B segments, L1-hot
// across waves); hi/lo bf16 split accumulated into the SAME fp32 C (exact).
// Counts via 1 LDS atomic per point. Flush via global atomics.
// ---------------------------------------------------------------------------
__global__ __launch_bounds__(512)
void reduce_kernel(const float* __restrict__ x,
                   const unsigned int* __restrict__ assign,
                   float* __restrict__ gsums, float* __restrict__ gcnt) {
    __shared__ float lds_cnt[K_CL];

    const int tid  = threadIdx.x;
    const int wave = tid >> 6;
    const int lane = tid & 63;
    const int l31  = lane & 31;
    const int h    = lane >> 5;

    lds_cnt[tid] = 0.f;   // blockDim == K_CL
    __syncthreads();

    const size_t pbase = (size_t)blockIdx.x * 2048;
#pragma unroll
    for (int i = 0; i < 4; ++i)
        atomicAdd(&lds_cnt[assign[pbase + tid + i * 512]], 1.f);

    const unsigned int row0 = wave * 64 + l31;
    const unsigned int row1 = row0 + 32;

    f32x16 C00 = {}, C01 = {}, C10 = {}, C11 = {};

    // prefetch chunk 0
    uint4 a_lo = *(const uint4*)(assign + pbase + 8 * h);
    uint4 a_hi = *(const uint4*)(assign + pbase + 8 * h + 4);
    float v0[8], v1[8];
    {
        const float* xp = x + (pbase + 8 * h) * DIM + l31;
#pragma unroll
        for (int j = 0; j < 8; ++j) {
            v0[j] = xp[(size_t)j * DIM];
            v1[j] = xp[(size_t)j * DIM + 32];
        }
    }

    for (int c = 0; c < 128; ++c) {
        unsigned int a[8] = {a_lo.x, a_lo.y, a_lo.z, a_lo.w,
                             a_hi.x, a_hi.y, a_hi.z, a_hi.w};
        float w0[8], w1[8];
#pragma unroll
        for (int j = 0; j < 8; ++j) { w0[j] = v0[j]; w1[j] = v1[j]; }

        // issue next chunk's loads before compute (latency hidden)
        if (c < 127) {
            const size_t p0n = pbase + (size_t)(c + 1) * 16;
            a_lo = *(const uint4*)(assign + p0n + 8 * h);
            a_hi = *(const uint4*)(assign + p0n + 8 * h + 4);
            const float* xp = x + (p0n + 8 * h) * DIM + l31;
#pragma unroll
            for (int j = 0; j < 8; ++j) {
                v0[j] = xp[(size_t)j * DIM];
                v1[j] = xp[(size_t)j * DIM + 32];
            }
        }

        // B fragments (hi/lo split, exact reconstruction in fp32 acc)
        short8 xh0, xl0, xh1, xl1;
        cvt8(w0, xh0, xl0);
        cvt8(w1, xh1, xl1);

        // A fragments: one-hot indicators, bf16 1.0 (exact)
        unsigned int i0[4], i1[4];
#pragma unroll
        for (int q = 0; q < 4; ++q) {
            i0[q] = (a[2*q] == row0 ? 0x3F80u : 0u) | (a[2*q+1] == row0 ? 0x3F800000u : 0u);
            i1[q] = (a[2*q] == row1 ? 0x3F80u : 0u) | (a[2*q+1] == row1 ? 0x3F800000u : 0u);
        }
        uint4 u0; u0.x = i0[0]; u0.y = i0[1]; u0.z = i0[2]; u0.w = i0[3];
        uint4 u1; u1.x = i1[0]; u1.y = i1[1]; u1.z = i1[2]; u1.w = i1[3];
        short8 A0 = __builtin_bit_cast(short8, u0);
        short8 A1 = __builtin_bit_cast(short8, u1);

        C00 = __builtin_amdgcn_mfma_f32_32x32x16_bf16(A0, xh0, C00, 0, 0, 0);
        C01 = __builtin_amdgcn_mfma_f32_32x32x16_bf16(A0, xh1, C01, 0, 0, 0);
        C10 = __builtin_amdgcn_mfma_f32_32x32x16_bf16(A1, xh0, C10, 0, 0, 0);
        C11 = __builtin_amdgcn_mfma_f32_32x32x16_bf16(A1, xh1, C11, 0, 0, 0);
        C00 = __builtin_amdgcn_mfma_f32_32x32x16_bf16(A0, xl0, C00, 0, 0, 0);
        C01 = __builtin_amdgcn_mfma_f32_32x32x16_bf16(A0, xl1, C01, 0, 0, 0);
        C10 = __builtin_amdgcn_mfma_f32_32x32x16_bf16(A1, xl0, C10, 0, 0, 0);
        C11 = __builtin_amdgcn_mfma_f32_32x32x16_bf16(A1, xl1, C11, 0, 0, 0);
    }

    __syncthreads();
    atomicAdd(&gcnt[tid], lds_cnt[tid]);

    // flush C tiles: center = base + (r&3)+8*(r>>2)+4h, dim = ct*32 + l31
#pragma unroll
    for (int r = 0; r < 16; ++r) {
        int ro = (r & 3) + 8 * (r >> 2) + 4 * h;
        atomicAdd(&gsums[(wave * 64 + ro) * DIM + l31],      C00[r]);
        atomicAdd(&gsums[(wave * 64 + ro) * DIM + 32 + l31], C01[r]);
        atomicAdd(&gsums[(wave * 64 + 32 + ro) * DIM + l31],      C10[r]);
        atomicAdd(&gsums[(wave * 64 + 32 + ro) * DIM + 32 + l31], C11[r]);
    }
}

// ---------------------------------------------------------------------------
// final: means + empty-cluster fallback + counts -> d_out
// ---------------------------------------------------------------------------
__global__ void final_kernel(const float* __restrict__ gsums,
                             const float* __restrict__ gcnt,
                             const float* __restrict__ centers,
                             float* __restrict__ out) {
    int i = blockIdx.x * 256 + threadIdx.x;
    if (i < K_CL * DIM) {
        int k = i >> 6;
        float c = gcnt[k];
        out[i] = (c > 0.f) ? (gsums[i] / c) : centers[i];
    } else if (i < OUTSZ) {
        out[i] = gcnt[i - K_CL * DIM];
    }
}

extern "C" void kernel_launch(void* const* d_in, const int* in_sizes, int n_in,
                              void* d_out, int out_size, void* d_ws, size_t ws_size,
                              hipStream_t stream) {
    const float* x       = (const float*)d_in[0];
    const float* centers = (const float*)d_in[1];

    char* ws = (char*)d_ws;
    unsigned short* chi    = (unsigned short*)(ws);             // 64 KiB
    unsigned short* clo    = (unsigned short*)(ws + 65536);     // 64 KiB
    float*          hc2    = (float*)(ws + 131072);             // 2 KiB
    unsigned int*   assign = (unsigned int*)(ws + 133120);      // 2 MiB
    float*          gsums  = (float*)(ws + 2230272);            // 128 KiB
    float*          gcnt   = (float*)(ws + 2361344);            // 2 KiB

    hipMemsetAsync(gsums, 0, (K_CL * DIM + K_CL) * sizeof(float), stream);
    prep_kernel<<<K_CL, 64, 0, stream>>>(centers, chi, clo, hc2);
    assign_kernel<<<2048, 512, 0, stream>>>(x, chi, clo, hc2, assign);
    reduce_kernel<<<256, 512, 0, stream>>>(x, assign, gsums, gcnt);
    final_kernel<<<(OUTSZ + 255) / 256, 256, 0, stream>>>(
        gsums, gcnt, centers, (float*)d_out);
}

// Round 8
// 194.100 us; speedup vs baseline: 2.2231x; 1.1616x over previous
//
#include <hip/hip_runtime.h>
#include <hip/hip_bf16.h>

typedef __attribute__((ext_vector_type(8)))  short short8;
typedef __attribute__((ext_vector_type(16))) float f32x16;

#define DIM   64
#define K_CL  512
#define N_PTS 524288
#define OUTSZ (K_CL * DIM + K_CL)   // 33280

// pack two fp32 -> one u32 of 2x bf16 (RNE) via compiler cvt_pk path
__device__ inline unsigned int pk_bf16(float a, float b) {
    float2 t; t.x = a; t.y = b;
    __hip_bfloat162 h2 = __float22bfloat162_rn(t);
    unsigned int u;
    __builtin_memcpy(&u, &h2, 4);
    return u;
}

// split float4 -> 2 u32 of bf16-hi, 2 u32 of bf16-lo
__device__ inline void split4(const float4& v, unsigned int hw[2], unsigned int lw[2]) {
    hw[0] = pk_bf16(v.x, v.y);
    hw[1] = pk_bf16(v.z, v.w);
    float hx = __builtin_bit_cast(float, hw[0] << 16);
    float hy = __builtin_bit_cast(float, hw[0] & 0xFFFF0000u);
    float hz = __builtin_bit_cast(float, hw[1] << 16);
    float hv = __builtin_bit_cast(float, hw[1] & 0xFFFF0000u);
    lw[0] = pk_bf16(v.x - hx, v.y - hy);
    lw[1] = pk_bf16(v.z - hz, v.w - hv);
}

// ---------------------------------------------------------------------------
// prep: one 64-lane block per center. hc2 = 0.5*||c||^2 (shuffle reduce);
// chi/clo = bf16 hi/lo of NEGATED center.
// ---------------------------------------------------------------------------
__global__ __launch_bounds__(64)
void prep_kernel(const float* __restrict__ c,
                 unsigned short* __restrict__ chi,
                 unsigned short* __restrict__ clo,
                 float* __restrict__ hc2) {
    const int k = blockIdx.x, d = threadIdx.x;
    float v = c[k * DIM + d];
    float s = v * v;
#pragma unroll
    for (int off = 1; off < 64; off <<= 1) s += __shfl_xor(s, off, 64);

    float nv = -v;
    unsigned int u  = __builtin_bit_cast(unsigned int, nv);
    unsigned int hr = (u + 0x7FFFu + ((u >> 16) & 1u)) & 0xFFFF0000u;
    chi[k * DIM + d] = (unsigned short)(hr >> 16);
    float lo = nv - __builtin_bit_cast(float, hr);
    unsigned int ul = __builtin_bit_cast(unsigned int, lo);
    unsigned int lr = ul + 0x7FFFu + ((ul >> 16) & 1u);
    clo[k * DIM + d] = (unsigned short)(lr >> 16);
    if (d == 0) hc2[k] = 0.5f * s;
}

// ---------------------------------------------------------------------------
// assign (unchanged from round 6): 2048 blocks x 512 thr, cooperative x
// staging, centers resident in VGPRs, u64 atomicMin winner.
// ---------------------------------------------------------------------------
__global__ __launch_bounds__(512, 4)
void assign_kernel(const float* __restrict__ x,
                   const unsigned short* __restrict__ chi_g,
                   const unsigned short* __restrict__ clo_g,
                   const float* __restrict__ hc2g,
                   unsigned int* __restrict__ assign) {
    __shared__ unsigned int lds_xh[1024];
    __shared__ unsigned int lds_xl[1024];
    __shared__ float lds_bias[512];
    __shared__ unsigned long long lds_best[256];

    const int tid  = threadIdx.x;
    const int wave = tid >> 6;
    const int lane = tid & 63;
    const int l31  = lane & 31;
    const int h    = lane >> 5;

    if (tid < 256) lds_best[tid] = ~0ull;
    {
        int w = tid >> 6, ct = (tid >> 5) & 1, hh = (tid >> 4) & 1, r = tid & 15;
        lds_bias[tid] = hc2g[w * 64 + ct * 32 + (r & 3) + 8 * (r >> 2) + 4 * hh];
    }

    short8 cH[2][4], cL[2][4];
#pragma unroll
    for (int ct = 0; ct < 2; ++ct) {
        int row = wave * 64 + ct * 32 + l31;
#pragma unroll
        for (int ks = 0; ks < 4; ++ks) {
            size_t off = (size_t)row * DIM + ks * 16 + h * 8;
            cH[ct][ks] = *(const short8*)(chi_g + off);
            cL[ct][ks] = *(const short8*)(clo_g + off);
        }
    }

    const int p_st  = tid >> 4;
    const int dgrp  = tid & 15;
    const int f_st  = dgrp >> 1;
    const int half  = dgrp & 1;
    const int widx  = f_st * 128 + ((p_st ^ (f_st & 7)) << 2) + half * 2;

    const size_t xbase = (size_t)blockIdx.x * 16384 + tid * 4;
    float4 pf = *(const float4*)(x + xbase);

    __syncthreads();

    const unsigned int base_id = wave * 64 + 4 * h;

    for (int t = 0; t < 8; ++t) {
        unsigned int hw2[2], lw2[2];
        split4(pf, hw2, lw2);
        { uint2 w2; w2.x = hw2[0]; w2.y = hw2[1]; *(uint2*)&lds_xh[widx] = w2; }
        { uint2 w2; w2.x = lw2[0]; w2.y = lw2[1]; *(uint2*)&lds_xl[widx] = w2; }
        __syncthreads();

        if (t < 7) pf = *(const float4*)(x + xbase + (size_t)(t + 1) * 2048);

        f32x16 acc0, acc1;
        {
            const float4* b0 = (const float4*)&lds_bias[wave * 64 + h * 16];
            const float4* b1 = (const float4*)&lds_bias[wave * 64 + 32 + h * 16];
#pragma unroll
            for (int g = 0; g < 4; ++g) {
                float4 a = b0[g], b = b1[g];
                acc0[4*g+0] = a.x; acc0[4*g+1] = a.y; acc0[4*g+2] = a.z; acc0[4*g+3] = a.w;
                acc1[4*g+0] = b.x; acc1[4*g+1] = b.y; acc1[4*g+2] = b.z; acc1[4*g+3] = b.w;
            }
        }

#pragma unroll
        for (int ks = 0; ks < 4; ++ks) {
            const int f = ks * 2 + h;
            const int ridx = f * 128 + ((l31 ^ (f & 7)) << 2);
            short8 xh = *(const short8*)&lds_xh[ridx];
            short8 xl = *(const short8*)&lds_xl[ridx];
            acc0 = __builtin_amdgcn_mfma_f32_32x32x16_bf16(cH[0][ks], xh, acc0, 0, 0, 0);
            acc1 = __builtin_amdgcn_mfma_f32_32x32x16_bf16(cH[1][ks], xh, acc1, 0, 0, 0);
            acc0 = __builtin_amdgcn_mfma_f32_32x32x16_bf16(cH[0][ks], xl, acc0, 0, 0, 0);
            acc1 = __builtin_amdgcn_mfma_f32_32x32x16_bf16(cH[1][ks], xl, acc1, 0, 0, 0);
            acc0 = __builtin_amdgcn_mfma_f32_32x32x16_bf16(cL[0][ks], xh, acc0, 0, 0, 0);
            acc1 = __builtin_amdgcn_mfma_f32_32x32x16_bf16(cL[1][ks], xh, acc1, 0, 0, 0);
        }

        float bv = acc0[0];
        unsigned int boff = 0;
#pragma unroll
        for (int r = 1; r < 16; ++r) {
            unsigned int off = (r & 3) + 8 * (r >> 2);
            if (acc0[r] < bv) { bv = acc0[r]; boff = off; }
        }
#pragma unroll
        for (int r = 0; r < 16; ++r) {
            unsigned int off = 32 + (r & 3) + 8 * (r >> 2);
            if (acc1[r] < bv) { bv = acc1[r]; boff = off; }
        }

        unsigned int ub = __builtin_bit_cast(unsigned int, bv);
        ub ^= (unsigned int)(((int)ub) >> 31) | 0x80000000u;
        unsigned long long pk =
            ((unsigned long long)ub << 32) | (unsigned long long)(base_id + boff);
        atomicMin(&lds_best[t * 32 + l31], pk);
        __syncthreads();
    }

    if (tid < 256)
        assign[blockIdx.x * 256 + tid] = (unsigned int)(lds_best[tid] & 0xFFFFFFFFu);
}

// ---------------------------------------------------------------------------
// reduce v3: one-hot MFMA with cooperative LDS staging.
// 256 blocks x 512 thr (8 waves), 2048 pts/block in 16 superchunks of 128.
// Staging: wave w = point-group w (16 pts), lane = dim; 16 coalesced loads,
// split hi/lo ONCE, write dim-major [64][128] u16 rows with XOR swizzle
// idx ^= (d&15)<<3 (same on write & read; rows d and d+32 share swizzle).
// Compute: per 16-pt chunk, 4 ds_read_b128 frags + in-reg one-hot + 8 MFMA.
// Double-buffered, loads for sc+1 issued before compute of sc (T14).
// ---------------------------------------------------------------------------
__global__ __launch_bounds__(512)
void reduce_kernel(const float* __restrict__ x,
                   const unsigned int* __restrict__ assign,
                   float* __restrict__ gsums, float* __restrict__ gcnt) {
    __shared__ unsigned short lds_h[2][64][128];
    __shared__ unsigned short lds_l[2][64][128];
    __shared__ unsigned int   lds_a[2][128];
    __shared__ float          lds_cnt[K_CL];

    const int tid  = threadIdx.x;
    const int wave = tid >> 6;
    const int lane = tid & 63;
    const int l31  = lane & 31;
    const int h    = lane >> 5;
    const int d    = lane;      // staging dim
    const int pg   = wave;      // staging point-group (16 pts)

    lds_cnt[tid] = 0.f;

    const size_t pbase = (size_t)blockIdx.x * 2048;

    float f[16];
    {   // issue loads for superchunk 0 (16 x coalesced 256B insts per wave)
        const float* xp = x + (pbase + pg * 16) * DIM + d;
#pragma unroll
        for (int i = 0; i < 16; ++i) f[i] = xp[(size_t)i * DIM];
    }
    __syncthreads();   // lds_cnt zeros visible

    // counts (overlap the load latency)
#pragma unroll
    for (int i = 0; i < 4; ++i)
        atomicAdd(&lds_cnt[assign[pbase + tid + i * 512]], 1.f);

    const int swz = (d & 15) << 3;

    // write staged registers into buffer b
#define WRITE_BUF(b)                                                          \
    {                                                                         \
        unsigned int hw[8], lw[8];                                            \
        _Pragma("unroll")                                                     \
        for (int q = 0; q < 8; ++q) {                                         \
            hw[q] = pk_bf16(f[2*q], f[2*q+1]);                                \
            float ha = __builtin_bit_cast(float, hw[q] << 16);                \
            float hb = __builtin_bit_cast(float, hw[q] & 0xFFFF0000u);        \
            lw[q] = pk_bf16(f[2*q] - ha, f[2*q+1] - hb);                      \
        }                                                                     \
        unsigned short* rh = &lds_h[b][d][0];                                 \
        unsigned short* rl = &lds_l[b][d][0];                                 \
        const int j0 = (pg * 16) ^ swz;                                       \
        const int j1 = (pg * 16 + 8) ^ swz;                                   \
        uint4 u;                                                              \
        u.x=hw[0]; u.y=hw[1]; u.z=hw[2]; u.w=hw[3]; *(uint4*)&rh[j0] = u;     \
        u.x=hw[4]; u.y=hw[5]; u.z=hw[6]; u.w=hw[7]; *(uint4*)&rh[j1] = u;     \
        u.x=lw[0]; u.y=lw[1]; u.z=lw[2]; u.w=lw[3]; *(uint4*)&rl[j0] = u;     \
        u.x=lw[4]; u.y=lw[5]; u.z=lw[6]; u.w=lw[7]; *(uint4*)&rl[j1] = u;     \
    }

    WRITE_BUF(0)
    if (tid < 32) {
        uint4 av = *(const uint4*)(assign + pbase + tid * 4);
        *(uint4*)&lds_a[0][tid * 4] = av;
    }
    __syncthreads();

    const unsigned int row0 = wave * 64 + l31;
    const unsigned int row1 = row0 + 32;
    f32x16 C00 = {}, C01 = {}, C10 = {}, C11 = {};

    for (int sc = 0; sc < 16; ++sc) {
        const int b = sc & 1;
        if (sc < 15) {   // issue next superchunk's loads under compute
            const float* xp = x + (pbase + (size_t)(sc + 1) * 128 + pg * 16) * DIM + d;
#pragma unroll
            for (int i = 0; i < 16; ++i) f[i] = xp[(size_t)i * DIM];
        }

#pragma unroll
        for (int c = 0; c < 8; ++c) {
            const unsigned int* ap = &lds_a[b][c * 16 + 8 * h];
            uint4 aA = *(const uint4*)ap;
            uint4 aB = *(const uint4*)(ap + 4);
            unsigned int a[8] = {aA.x, aA.y, aA.z, aA.w, aB.x, aB.y, aB.z, aB.w};
            unsigned int i0[4], i1[4];
#pragma unroll
            for (int q = 0; q < 4; ++q) {
                i0[q] = (a[2*q]==row0 ? 0x3F80u : 0u) | (a[2*q+1]==row0 ? 0x3F800000u : 0u);
                i1[q] = (a[2*q]==row1 ? 0x3F80u : 0u) | (a[2*q+1]==row1 ? 0x3F800000u : 0u);
            }
            uint4 u0; u0.x=i0[0]; u0.y=i0[1]; u0.z=i0[2]; u0.w=i0[3];
            uint4 u1; u1.x=i1[0]; u1.y=i1[1]; u1.z=i1[2]; u1.w=i1[3];
            short8 A0 = __builtin_bit_cast(short8, u0);
            short8 A1 = __builtin_bit_cast(short8, u1);

            const int off = (c * 16 + 8 * h) ^ ((l31 & 15) << 3);
            short8 xh0 = *(const short8*)&lds_h[b][l31][off];
            short8 xh1 = *(const short8*)&lds_h[b][l31 + 32][off];
            short8 xl0 = *(const short8*)&lds_l[b][l31][off];
            short8 xl1 = *(const short8*)&lds_l[b][l31 + 32][off];

            C00 = __builtin_amdgcn_mfma_f32_32x32x16_bf16(A0, xh0, C00, 0, 0, 0);
            C01 = __builtin_amdgcn_mfma_f32_32x32x16_bf16(A0, xh1, C01, 0, 0, 0);
            C10 = __builtin_amdgcn_mfma_f32_32x32x16_bf16(A1, xh0, C10, 0, 0, 0);
            C11 = __builtin_amdgcn_mfma_f32_32x32x16_bf16(A1, xh1, C11, 0, 0, 0);
            C00 = __builtin_amdgcn_mfma_f32_32x32x16_bf16(A0, xl0, C00, 0, 0, 0);
            C01 = __builtin_amdgcn_mfma_f32_32x32x16_bf16(A0, xl1, C01, 0, 0, 0);
            C10 = __builtin_amdgcn_mfma_f32_32x32x16_bf16(A1, xl0, C10, 0, 0, 0);
            C11 = __builtin_amdgcn_mfma_f32_32x32x16_bf16(A1, xl1, C11, 0, 0, 0);
        }
        __syncthreads();   // all waves done reading buf b

        if (sc < 15) {
            WRITE_BUF(b ^ 1)
            if (tid < 32) {
                uint4 av = *(const uint4*)(assign + pbase + (size_t)(sc + 1) * 128 + tid * 4);
                *(uint4*)&lds_a[b ^ 1][tid * 4] = av;
            }
            __syncthreads();   // buf b^1 staged for next iteration
        }
    }
#undef WRITE_BUF

    atomicAdd(&gcnt[tid], lds_cnt[tid]);

    // flush C tiles: center = wave*64 (+32) + (r&3)+8*(r>>2)+4h, dim = l31 / l31+32
#pragma unroll
    for (int r = 0; r < 16; ++r) {
        int ro = (r & 3) + 8 * (r >> 2) + 4 * h;
        atomicAdd(&gsums[(wave * 64 + ro) * DIM + l31],           C00[r]);
        atomicAdd(&gsums[(wave * 64 + ro) * DIM + 32 + l31],      C01[r]);
        atomicAdd(&gsums[(wave * 64 + 32 + ro) * DIM + l31],      C10[r]);
        atomicAdd(&gsums[(wave * 64 + 32 + ro) * DIM + 32 + l31], C11[r]);
    }
}

// ---------------------------------------------------------------------------
// final: means + empty-cluster fallback + counts -> d_out
// ---------------------------------------------------------------------------
__global__ void final_kernel(const float* __restrict__ gsums,
                             const float* __restrict__ gcnt,
                             const float* __restrict__ centers,
                             float* __restrict__ out) {
    int i = blockIdx.x * 256 + threadIdx.x;
    if (i < K_CL * DIM) {
        int k = i >> 6;
        float c = gcnt[k];
        out[i] = (c > 0.f) ? (gsums[i] / c) : centers[i];
    } else if (i < OUTSZ) {
        out[i] = gcnt[i - K_CL * DIM];
    }
}

extern "C" void kernel_launch(void* const* d_in, const int* in_sizes, int n_in,
                              void* d_out, int out_size, void* d_ws, size_t ws_size,
                              hipStream_t stream) {
    const float* x       = (const float*)d_in[0];
    const float* centers = (const float*)d_in[1];

    char* ws = (char*)d_ws;
    unsigned short* chi    = (unsigned short*)(ws);             // 64 KiB
    unsigned short* clo    = (unsigned short*)(ws + 65536);     // 64 KiB
    float*          hc2    = (float*)(ws + 131072);             // 2 KiB
    unsigned int*   assign = (unsigned int*)(ws + 133120);      // 2 MiB
    float*          gsums  = (float*)(ws + 2230272);            // 128 KiB
    float*          gcnt   = (float*)(ws + 2361344);            // 2 KiB

    hipMemsetAsync(gsums, 0, (K_CL * DIM + K_CL) * sizeof(float), stream);
    prep_kernel<<<K_CL, 64, 0, stream>>>(centers, chi, clo, hc2);
    assign_kernel<<<2048, 512, 0, stream>>>(x, chi, clo, hc2, assign);
    reduce_kernel<<<256, 512, 0, stream>>>(x, assign, gsums, gcnt);
    final_kernel<<<(OUTSZ + 255) / 256, 256, 0, stream>>>(
        gsums, gcnt, centers, (float*)d_out);
}

// Round 9
// 188.739 us; speedup vs baseline: 2.2862x; 1.0284x over previous
//
#include <hip/hip_runtime.h>
#include <hip/hip_bf16.h>

typedef __attribute__((ext_vector_type(8)))  short short8;
typedef __attribute__((ext_vector_type(16))) float f32x16;

#define DIM   64
#define K_CL  512
#define N_PTS 524288
#define OUTSZ (K_CL * DIM + K_CL)   // 33280

// pack two fp32 -> one u32 of 2x bf16 (RNE) via compiler cvt_pk path
__device__ inline unsigned int pk_bf16(float a, float b) {
    float2 t; t.x = a; t.y = b;
    __hip_bfloat162 h2 = __float22bfloat162_rn(t);
    unsigned int u;
    __builtin_memcpy(&u, &h2, 4);
    return u;
}

// split float4 -> 2 u32 of bf16-hi, 2 u32 of bf16-lo
__device__ inline void split4(const float4& v, unsigned int hw[2], unsigned int lw[2]) {
    hw[0] = pk_bf16(v.x, v.y);
    hw[1] = pk_bf16(v.z, v.w);
    float hx = __builtin_bit_cast(float, hw[0] << 16);
    float hy = __builtin_bit_cast(float, hw[0] & 0xFFFF0000u);
    float hz = __builtin_bit_cast(float, hw[1] << 16);
    float hv = __builtin_bit_cast(float, hw[1] & 0xFFFF0000u);
    lw[0] = pk_bf16(v.x - hx, v.y - hy);
    lw[1] = pk_bf16(v.z - hz, v.w - hv);
}

// ---------------------------------------------------------------------------
// prep: one 64-lane block per center. hc2 = 0.5*||c||^2 (shuffle reduce);
// chi/clo = bf16 hi/lo of NEGATED center.
// ---------------------------------------------------------------------------
__global__ __launch_bounds__(64)
void prep_kernel(const float* __restrict__ c,
                 unsigned short* __restrict__ chi,
                 unsigned short* __restrict__ clo,
                 float* __restrict__ hc2) {
    const int k = blockIdx.x, d = threadIdx.x;
    float v = c[k * DIM + d];
    float s = v * v;
#pragma unroll
    for (int off = 1; off < 64; off <<= 1) s += __shfl_xor(s, off, 64);

    float nv = -v;
    unsigned int u  = __builtin_bit_cast(unsigned int, nv);
    unsigned int hr = (u + 0x7FFFu + ((u >> 16) & 1u)) & 0xFFFF0000u;
    chi[k * DIM + d] = (unsigned short)(hr >> 16);
    float lo = nv - __builtin_bit_cast(float, hr);
    unsigned int ul = __builtin_bit_cast(unsigned int, lo);
    unsigned int lr = ul + 0x7FFFu + ((ul >> 16) & 1u);
    clo[k * DIM + d] = (unsigned short)(lr >> 16);
    if (d == 0) hc2[k] = 0.5f * s;
}

// ---------------------------------------------------------------------------
// assign v2: 2048 blocks x 512 thr (8 waves), 8 tiles of 32 points.
// Double-buffered x staging -> ONE barrier per tile: between barriers,
// reads hit buf[b] and writes hit buf[b^1] (disjoint). Depth-2 global
// prefetch covers HBM latency under the 24-MFMA compute. Centers resident
// in VGPRs; bias (0.5||c||^2) via LDS broadcast; u64 atomicMin winner.
// ---------------------------------------------------------------------------
__global__ __launch_bounds__(512, 4)
void assign_kernel(const float* __restrict__ x,
                   const unsigned short* __restrict__ chi_g,
                   const unsigned short* __restrict__ clo_g,
                   const float* __restrict__ hc2g,
                   unsigned int* __restrict__ assign) {
    __shared__ unsigned int lds_xh[2][1024];
    __shared__ unsigned int lds_xl[2][1024];
    __shared__ float lds_bias[512];
    __shared__ unsigned long long lds_best[256];

    const int tid  = threadIdx.x;
    const int wave = tid >> 6;
    const int lane = tid & 63;
    const int l31  = lane & 31;
    const int h    = lane >> 5;

    if (tid < 256) lds_best[tid] = ~0ull;
    {
        int w = tid >> 6, ct = (tid >> 5) & 1, hh = (tid >> 4) & 1, r = tid & 15;
        lds_bias[tid] = hc2g[w * 64 + ct * 32 + (r & 3) + 8 * (r >> 2) + 4 * hh];
    }

    short8 cH[2][4], cL[2][4];
#pragma unroll
    for (int ct = 0; ct < 2; ++ct) {
        int row = wave * 64 + ct * 32 + l31;
#pragma unroll
        for (int ks = 0; ks < 4; ++ks) {
            size_t off = (size_t)row * DIM + ks * 16 + h * 8;
            cH[ct][ks] = *(const short8*)(chi_g + off);
            cL[ct][ks] = *(const short8*)(clo_g + off);
        }
    }

    // staging map: thread stages point p_st = tid>>4, dims 4*(tid&15)..+3
    const int p_st  = tid >> 4;
    const int dgrp  = tid & 15;
    const int f_st  = dgrp >> 1;
    const int half  = dgrp & 1;
    const int widx  = f_st * 128 + ((p_st ^ (f_st & 7)) << 2) + half * 2;

    const size_t xbase = (size_t)blockIdx.x * 16384 + tid * 4;

#define STAGE(buf, v4)                                                        \
    {                                                                         \
        unsigned int hw2[2], lw2[2];                                          \
        split4(v4, hw2, lw2);                                                 \
        uint2 w2;                                                             \
        w2.x = hw2[0]; w2.y = hw2[1]; *(uint2*)&lds_xh[buf][widx] = w2;       \
        w2.x = lw2[0]; w2.y = lw2[1]; *(uint2*)&lds_xl[buf][widx] = w2;       \
    }

    // prologue: stage tile 0, prefetch tile 1
    float4 pf = *(const float4*)(x + xbase);
    STAGE(0, pf)
    pf = *(const float4*)(x + xbase + 2048);
    __syncthreads();

    const unsigned int base_id = wave * 64 + 4 * h;

    for (int t = 0; t < 8; ++t) {
        const int b = t & 1;
        if (t < 7) STAGE(b ^ 1, pf)                     // stage tile t+1
        if (t < 6) pf = *(const float4*)(x + xbase + (size_t)(t + 2) * 2048);

        // acc init from LDS bias table (broadcast b128 reads)
        f32x16 acc0, acc1;
        {
            const float4* b0 = (const float4*)&lds_bias[wave * 64 + h * 16];
            const float4* b1 = (const float4*)&lds_bias[wave * 64 + 32 + h * 16];
#pragma unroll
            for (int g = 0; g < 4; ++g) {
                float4 a = b0[g], bb = b1[g];
                acc0[4*g+0] = a.x;  acc0[4*g+1] = a.y;  acc0[4*g+2] = a.z;  acc0[4*g+3] = a.w;
                acc1[4*g+0] = bb.x; acc1[4*g+1] = bb.y; acc1[4*g+2] = bb.z; acc1[4*g+3] = bb.w;
            }
        }

#pragma unroll
        for (int ks = 0; ks < 4; ++ks) {
            const int f = ks * 2 + h;
            const int ridx = f * 128 + ((l31 ^ (f & 7)) << 2);
            short8 xh = *(const short8*)&lds_xh[b][ridx];
            short8 xl = *(const short8*)&lds_xl[b][ridx];
            acc0 = __builtin_amdgcn_mfma_f32_32x32x16_bf16(cH[0][ks], xh, acc0, 0, 0, 0);
            acc1 = __builtin_amdgcn_mfma_f32_32x32x16_bf16(cH[1][ks], xh, acc1, 0, 0, 0);
            acc0 = __builtin_amdgcn_mfma_f32_32x32x16_bf16(cH[0][ks], xl, acc0, 0, 0, 0);
            acc1 = __builtin_amdgcn_mfma_f32_32x32x16_bf16(cH[1][ks], xl, acc1, 0, 0, 0);
            acc0 = __builtin_amdgcn_mfma_f32_32x32x16_bf16(cL[0][ks], xh, acc0, 0, 0, 0);
            acc1 = __builtin_amdgcn_mfma_f32_32x32x16_bf16(cL[1][ks], xh, acc1, 0, 0, 0);
        }

        // in-lane argmin, ids ascending -> strict < = first occurrence
        float bv = acc0[0];
        unsigned int boff = 0;
#pragma unroll
        for (int r = 1; r < 16; ++r) {
            unsigned int off = (r & 3) + 8 * (r >> 2);
            if (acc0[r] < bv) { bv = acc0[r]; boff = off; }
        }
#pragma unroll
        for (int r = 0; r < 16; ++r) {
            unsigned int off = 32 + (r & 3) + 8 * (r >> 2);
            if (acc1[r] < bv) { bv = acc1[r]; boff = off; }
        }

        unsigned int ub = __builtin_bit_cast(unsigned int, bv);
        ub ^= (unsigned int)(((int)ub) >> 31) | 0x80000000u;
        unsigned long long pk =
            ((unsigned long long)ub << 32) | (unsigned long long)(base_id + boff);
        atomicMin(&lds_best[t * 32 + l31], pk);
        __syncthreads();          // the ONLY barrier per tile
    }
#undef STAGE

    if (tid < 256)
        assign[blockIdx.x * 256 + tid] = (unsigned int)(lds_best[tid] & 0xFFFFFFFFu);
}

// ---------------------------------------------------------------------------
// reduce v4: one-hot MFMA, bf16-HI ONLY (mean error ~5e-5, far under the 2%
// threshold). 512 blocks x 512 thr, 1024 pts/block in 8 superchunks of 128.
// Dim-major LDS [64][128] u16, XOR swizzle (d&15)<<3 on write & read.
// Per 16-pt chunk: 2 ds_read_b128 + one-hot + 4 MFMA. Double-buffered.
// ---------------------------------------------------------------------------
__global__ __launch_bounds__(512)
void reduce_kernel(const float* __restrict__ x,
                   const unsigned int* __restrict__ assign,
                   float* __restrict__ gsums, float* __restrict__ gcnt) {
    __shared__ unsigned short lds_h[2][64][128];
    __shared__ unsigned int   lds_a[2][128];
    __shared__ float          lds_cnt[K_CL];

    const int tid  = threadIdx.x;
    const int wave = tid >> 6;
    const int lane = tid & 63;
    const int l31  = lane & 31;
    const int h    = lane >> 5;
    const int d    = lane;      // staging dim
    const int pg   = wave;      // staging point-group (16 pts)

    lds_cnt[tid] = 0.f;

    const size_t pbase = (size_t)blockIdx.x * 1024;

    float f[16];
    {
        const float* xp = x + (pbase + pg * 16) * DIM + d;
#pragma unroll
        for (int i = 0; i < 16; ++i) f[i] = xp[(size_t)i * DIM];
    }
    __syncthreads();   // lds_cnt zeros visible

#pragma unroll
    for (int i = 0; i < 2; ++i)
        atomicAdd(&lds_cnt[assign[pbase + tid + i * 512]], 1.f);

    const int swz = (d & 15) << 3;

#define WRITE_BUF(b)                                                          \
    {                                                                         \
        unsigned int hw[8];                                                   \
        _Pragma("unroll")                                                     \
        for (int q = 0; q < 8; ++q) hw[q] = pk_bf16(f[2*q], f[2*q+1]);        \
        unsigned short* rh = &lds_h[b][d][0];                                 \
        const int j0 = (pg * 16) ^ swz;                                       \
        const int j1 = (pg * 16 + 8) ^ swz;                                   \
        uint4 u;                                                              \
        u.x=hw[0]; u.y=hw[1]; u.z=hw[2]; u.w=hw[3]; *(uint4*)&rh[j0] = u;     \
        u.x=hw[4]; u.y=hw[5]; u.z=hw[6]; u.w=hw[7]; *(uint4*)&rh[j1] = u;     \
    }

    WRITE_BUF(0)
    if (tid < 32) {
        uint4 av = *(const uint4*)(assign + pbase + tid * 4);
        *(uint4*)&lds_a[0][tid * 4] = av;
    }
    __syncthreads();

    const unsigned int row0 = wave * 64 + l31;
    const unsigned int row1 = row0 + 32;
    f32x16 C00 = {}, C01 = {}, C10 = {}, C11 = {};

    for (int sc = 0; sc < 8; ++sc) {
        const int b = sc & 1;
        if (sc < 7) {
            const float* xp = x + (pbase + (size_t)(sc + 1) * 128 + pg * 16) * DIM + d;
#pragma unroll
            for (int i = 0; i < 16; ++i) f[i] = xp[(size_t)i * DIM];
        }

#pragma unroll
        for (int c = 0; c < 8; ++c) {
            const unsigned int* ap = &lds_a[b][c * 16 + 8 * h];
            uint4 aA = *(const uint4*)ap;
            uint4 aB = *(const uint4*)(ap + 4);
            unsigned int a[8] = {aA.x, aA.y, aA.z, aA.w, aB.x, aB.y, aB.z, aB.w};
            unsigned int i0[4], i1[4];
#pragma unroll
            for (int q = 0; q < 4; ++q) {
                i0[q] = (a[2*q]==row0 ? 0x3F80u : 0u) | (a[2*q+1]==row0 ? 0x3F800000u : 0u);
                i1[q] = (a[2*q]==row1 ? 0x3F80u : 0u) | (a[2*q+1]==row1 ? 0x3F800000u : 0u);
            }
            uint4 u0; u0.x=i0[0]; u0.y=i0[1]; u0.z=i0[2]; u0.w=i0[3];
            uint4 u1; u1.x=i1[0]; u1.y=i1[1]; u1.z=i1[2]; u1.w=i1[3];
            short8 A0 = __builtin_bit_cast(short8, u0);
            short8 A1 = __builtin_bit_cast(short8, u1);

            const int off = (c * 16 + 8 * h) ^ ((l31 & 15) << 3);
            short8 xh0 = *(const short8*)&lds_h[b][l31][off];
            short8 xh1 = *(const short8*)&lds_h[b][l31 + 32][off];

            C00 = __builtin_amdgcn_mfma_f32_32x32x16_bf16(A0, xh0, C00, 0, 0, 0);
            C01 = __builtin_amdgcn_mfma_f32_32x32x16_bf16(A0, xh1, C01, 0, 0, 0);
            C10 = __builtin_amdgcn_mfma_f32_32x32x16_bf16(A1, xh0, C10, 0, 0, 0);
            C11 = __builtin_amdgcn_mfma_f32_32x32x16_bf16(A1, xh1, C11, 0, 0, 0);
        }
        __syncthreads();

        if (sc < 7) {
            WRITE_BUF(b ^ 1)
            if (tid < 32) {
                uint4 av = *(const uint4*)(assign + pbase + (size_t)(sc + 1) * 128 + tid * 4);
                *(uint4*)&lds_a[b ^ 1][tid * 4] = av;
            }
            __syncthreads();
        }
    }
#undef WRITE_BUF

    atomicAdd(&gcnt[tid], lds_cnt[tid]);

    const int rot = (int)((blockIdx.x * 1013904223u) >> 23) & (K_CL - 1);
#pragma unroll
    for (int r = 0; r < 16; ++r) {
        int ro = (r & 3) + 8 * (r >> 2) + 4 * h;
        int k0 = (wave * 64 + ro + rot) & (K_CL - 1);
        int k1 = (wave * 64 + 32 + ro + rot) & (K_CL - 1);
        // rotation changes which k each C row targets? NO -- C rows are fixed.
        // rotate only the ORDER of the 16 flush iterations instead:
        (void)k0; (void)k1;
    }
#pragma unroll
    for (int rr = 0; rr < 16; ++rr) {
        int r = (rr + (int)(blockIdx.x & 15)) & 15;   // stagger flush order
        int ro = (r & 3) + 8 * (r >> 2) + 4 * h;
        atomicAdd(&gsums[(wave * 64 + ro) * DIM + l31],           C00[r]);
        atomicAdd(&gsums[(wave * 64 + ro) * DIM + 32 + l31],      C01[r]);
        atomicAdd(&gsums[(wave * 64 + 32 + ro) * DIM + l31],      C10[r]);
        atomicAdd(&gsums[(wave * 64 + 32 + ro) * DIM + 32 + l31], C11[r]);
    }
}

// ---------------------------------------------------------------------------
// final: means + empty-cluster fallback + counts -> d_out
// ---------------------------------------------------------------------------
__global__ void final_kernel(const float* __restrict__ gsums,
                             const float* __restrict__ gcnt,
                             const float* __restrict__ centers,
                             float* __restrict__ out) {
    int i = blockIdx.x * 256 + threadIdx.x;
    if (i < K_CL * DIM) {
        int k = i >> 6;
        float c = gcnt[k];
        out[i] = (c > 0.f) ? (gsums[i] / c) : centers[i];
    } else if (i < OUTSZ) {
        out[i] = gcnt[i - K_CL * DIM];
    }
}

extern "C" void kernel_launch(void* const* d_in, const int* in_sizes, int n_in,
                              void* d_out, int out_size, void* d_ws, size_t ws_size,
                              hipStream_t stream) {
    const float* x       = (const float*)d_in[0];
    const float* centers = (const float*)d_in[1];

    char* ws = (char*)d_ws;
    unsigned short* chi    = (unsigned short*)(ws);             // 64 KiB
    unsigned short* clo    = (unsigned short*)(ws + 65536);     // 64 KiB
    float*          hc2    = (float*)(ws + 131072);             // 2 KiB
    unsigned int*   assign = (unsigned int*)(ws + 133120);      // 2 MiB
    float*          gsums  = (float*)(ws + 2230272);            // 128 KiB
    float*          gcnt   = (float*)(ws + 2361344);            // 2 KiB

    hipMemsetAsync(gsums, 0, (K_CL * DIM + K_CL) * sizeof(float), stream);
    prep_kernel<<<K_CL, 64, 0, stream>>>(centers, chi, clo, hc2);
    assign_kernel<<<2048, 512, 0, stream>>>(x, chi, clo, hc2, assign);
    reduce_kernel<<<512, 512, 0, stream>>>(x, assign, gsums, gcnt);
    final_kernel<<<(OUTSZ + 255) / 256, 256, 0, stream>>>(
        gsums, gcnt, centers, (float*)d_out);
}